// Round 4
// baseline (74.119 us; speedup 1.0000x reference)
//
#include <hip/hip_runtime.h>

#define BLOCK 256
#define CHUNK 64            // n-points staged per block (small: lets grid.y=64 keep occupancy at MPT=4)
#define MPT   4             // m-points per thread: amortize the LDS broadcast 4x
#define LOG2E 1.44269504088896340736f

// v(p_m) = sum_n exp(-|p_m - g_n|^2) * c_n   (SIGMA = 1)
// exp(-|p-g|^2) = exp(-|p|^2) * [exp(-|g|^2)] * exp2(2*log2e * p.g)
//
// Experiment history:
//   R0 (69.2us): CHUNK=256, MPT=1, atomics  -> per-CU LDS pipe: 16w x 256 x 12cy = 20.5us (bound)
//   R1 (77.5us): MPT=4 but 256 blocks total -> 1 wave/SIMD, latency-exposed (occupancy, not MPT, lost)
//   R2 (77.4us): no LDS, in-loop global loads -> load-latency-bound
//   R3 (70.4us): partials+reduce ~= atomics -> write path not the bottleneck
// This round: the untested cell — MPT=4 WITH occupancy held at 16 waves/CU.
// CHUNK=64, grid=(16,64)=1024 blocks of 256 (same as R0). Per-CU LDS falls
// 4x to ~5.1us; VALU ~3.4us/SIMD; trans ~3.4us -> compute-bound floor ~7-10us.
__global__ void __launch_bounds__(BLOCK)
translations_partial(const float* __restrict__ gd,
                     const float* __restrict__ controls,
                     const float* __restrict__ points,
                     float* __restrict__ ws,   // [nchunks][M] float2 partials
                     int N, int M) {
    __shared__ float4 sg[CHUNK];

    const int tid = threadIdx.x;
    const int n0  = blockIdx.y * CHUNK;

    // Stage chunk: (gx, gy, c0*exp(-|g|^2), c1*exp(-|g|^2)); zero-pad OOB so the
    // main loop needs no tail handling (w * 0 == 0).
    if (tid < CHUNK) {
        const int n = n0 + tid;
        if (n < N) {
            float2 g = ((const float2*)gd)[n];
            float2 c = ((const float2*)controls)[n];
            float  e = __expf(-(g.x * g.x + g.y * g.y));
            sg[tid] = make_float4(g.x, g.y, c.x * e, c.y * e);
        } else {
            sg[tid] = make_float4(0.f, 0.f, 0.f, 0.f);
        }
    }
    __syncthreads();

    // Each thread owns MPT m-points, strided by BLOCK for coalesced access.
    const int mbase = blockIdx.x * (BLOCK * MPT) + tid;

    float a0[MPT], a1[MPT], acc0[MPT], acc1[MPT];
#pragma unroll
    for (int k = 0; k < MPT; ++k) {
        const int m = mbase + k * BLOCK;
        float2 p = (m < M) ? ((const float2*)points)[m] : make_float2(0.f, 0.f);
        a0[k] = (2.0f * LOG2E) * p.x;
        a1[k] = (2.0f * LOG2E) * p.y;
        acc0[k] = 0.f;  acc1[k] = 0.f;
    }

#pragma unroll 8
    for (int j = 0; j < CHUNK; ++j) {
        float4 g = sg[j];                          // wave-uniform addr -> LDS broadcast
#pragma unroll
        for (int k = 0; k < MPT; ++k) {            // 4 independent chains: ILP across pipes
            float t = fmaf(a0[k], g.x, a1[k] * g.y);   // 2*log2e * (p . g)
            float w = __builtin_amdgcn_exp2f(t);       // v_exp_f32
            acc0[k] = fmaf(w, g.z, acc0[k]);
            acc1[k] = fmaf(w, g.w, acc1[k]);
        }
    }

    float2* wrow = (float2*)ws + (size_t)blockIdx.y * M;
#pragma unroll
    for (int k = 0; k < MPT; ++k) {
        const int m = mbase + k * BLOCK;
        if (m < M) {
            // s = exp(-|p|^2), recomputed from a0,a1 (saves 8 VGPRs of px/py):
            // |p|^2 = (a0^2+a1^2)/(4*LOG2E^2)  =>  -LOG2E*|p|^2 = -(a0^2+a1^2)/(4*LOG2E)
            float q = fmaf(a0[k], a0[k], a1[k] * a1[k]);
            float s = __builtin_amdgcn_exp2f(q * (-0.25f / LOG2E));
            wrow[m] = make_float2(acc0[k] * s, acc1[k] * s);
        }
    }
}

// Sum nchunks partials per output COMPONENT (i in [0, 2M)); writes every out
// element exactly once (overwrites poison; no memset dispatch needed).
template <int NC>
__global__ void __launch_bounds__(BLOCK)
translations_reduce(const float* __restrict__ ws, float* __restrict__ out, int M2) {
    const int i = blockIdx.x * BLOCK + threadIdx.x;
    if (i >= M2) return;
    float a = 0.f;
#pragma unroll 16
    for (int c = 0; c < NC; ++c)
        a += ws[(size_t)c * M2 + i];               // coalesced: lanes -> consecutive floats
    out[i] = a;
}

__global__ void __launch_bounds__(BLOCK)
translations_reduce_dyn(const float* __restrict__ ws, float* __restrict__ out,
                        int M2, int nchunks) {
    const int i = blockIdx.x * BLOCK + threadIdx.x;
    if (i >= M2) return;
    float a = 0.f;
    for (int c = 0; c < nchunks; ++c)
        a += ws[(size_t)c * M2 + i];
    out[i] = a;
}

// Fallback (ws too small): R0's proven memset+atomic path, CHUNK=256 geometry.
#define ATCHUNK 256
__global__ void __launch_bounds__(BLOCK)
translations_atomic(const float* __restrict__ gd,
                    const float* __restrict__ controls,
                    const float* __restrict__ points,
                    float* __restrict__ out, int N, int M) {
    __shared__ float4 sg[ATCHUNK];
    const int tid = threadIdx.x;
    const int m   = blockIdx.x * BLOCK + tid;
    const int n0  = blockIdx.y * ATCHUNK;
    {
        const int n = n0 + tid;
        if (n < N) {
            float2 g = ((const float2*)gd)[n];
            float2 c = ((const float2*)controls)[n];
            float  e = __expf(-(g.x * g.x + g.y * g.y));
            sg[tid] = make_float4(g.x, g.y, c.x * e, c.y * e);
        } else {
            sg[tid] = make_float4(0.f, 0.f, 0.f, 0.f);
        }
    }
    __syncthreads();
    if (m >= M) return;
    const float2 p  = ((const float2*)points)[m];
    const float  a0 = (2.0f * LOG2E) * p.x;
    const float  a1 = (2.0f * LOG2E) * p.y;
    float acc0 = 0.f, acc1 = 0.f;
#pragma unroll 8
    for (int j = 0; j < ATCHUNK; ++j) {
        float4 g = sg[j];
        float  t = fmaf(a0, g.x, a1 * g.y);
        float  w = __builtin_amdgcn_exp2f(t);
        acc0 = fmaf(w, g.z, acc0);
        acc1 = fmaf(w, g.w, acc1);
    }
    const float s = __expf(-(p.x * p.x + p.y * p.y));
    atomicAdd(&out[2 * m],     acc0 * s);
    atomicAdd(&out[2 * m + 1], acc1 * s);
}

extern "C" void kernel_launch(void* const* d_in, const int* in_sizes, int n_in,
                              void* d_out, int out_size, void* d_ws, size_t ws_size,
                              hipStream_t stream) {
    const float* gd       = (const float*)d_in[0];  // [N*2]
    const float* controls = (const float*)d_in[1];  // [N*2]
    const float* points   = (const float*)d_in[2];  // [M,2]
    float* out = (float*)d_out;                     // [M,2] fp32

    const int N = in_sizes[0] / 2;
    const int M = in_sizes[2] / 2;

    const int nchunks = (N + CHUNK - 1) / CHUNK;    // 64 for N=4096
    const size_t ws_need = (size_t)nchunks * (size_t)M * 2 * sizeof(float);  // 8 MB

    if (ws_size >= ws_need && d_ws != nullptr) {
        float* ws = (float*)d_ws;
        dim3 gridA((M + BLOCK * MPT - 1) / (BLOCK * MPT), nchunks);  // (16, 64)
        translations_partial<<<gridA, dim3(BLOCK), 0, stream>>>(
            gd, controls, points, ws, N, M);
        const int M2 = 2 * M;
        dim3 gridB((M2 + BLOCK - 1) / BLOCK);                        // 128 blocks
        if (nchunks == 64) {
            translations_reduce<64><<<gridB, dim3(BLOCK), 0, stream>>>(ws, out, M2);
        } else {
            translations_reduce_dyn<<<gridB, dim3(BLOCK), 0, stream>>>(ws, out, M2, nchunks);
        }
    } else {
        // d_out is poisoned with 0xAA before every timed launch; atomics need zeros.
        hipMemsetAsync(d_out, 0, (size_t)out_size * sizeof(float), stream);
        dim3 gridA((M + BLOCK - 1) / BLOCK, (N + ATCHUNK - 1) / ATCHUNK);
        translations_atomic<<<gridA, dim3(BLOCK), 0, stream>>>(gd, controls, points, out, N, M);
    }
}